// Round 5
// baseline (56794.409 us; speedup 1.0000x reference)
//
#include <hip/hip_runtime.h>
#include <math.h>

// LSTMNN: T=1024, B=64, I=128, H=512, L=2, fp32.
// Round 5: persistent kernel, 256 WGs x 512 thr.
//   - R4 counters: sc0/sc1 act reads bypass L2 -> 128 MB/step served by IF$
//     (FETCH_SIZE stayed tiny => IF$ absorbed it). All 32 WGs/XCD read the
//     SAME acts; sc reads forfeit that 32x L2 sharing.
//   - NEW: act reads are normal cached loads; ONE agent acquire fence
//     (buffer_inv) per step after barrier exit invalidates L1+L2, so each
//     XCD fetches acts from IF$ once (~4 MB/step total) and L2 serves the
//     rest. Stores remain sc0/sc1 write-through (no dirty L2, no wbl2).
//   - Per-thread-fixed weights (w_out/w_in rows, biases) cached in VGPRs:
//     invalidation-immune, removes ~24 MB/step of post-inv refetch.
//   - Barrier polls use explicit sc0/sc1 loads (guaranteed coherent).

namespace {
constexpr int T_STEPS = 1024;
constexpr int B = 64;
constexpr int I_DIM = 128;
constexpr int H = 512;
constexpr int NBLK = 256;
constexpr int NTHR = 512;
constexpr int HB = H * B;  // 32768
constexpr int P = 20;      // padded chunk dim for LDS weights

// ws layout (floats)
constexpr int OFF_INP  = 0;                  // [2][512][64] inp^T parity
constexpr int OFF_H0   = OFF_INP + 2 * HB;   // [2][512][64] h0^T parity
constexpr int OFF_H1   = OFF_H0 + 2 * HB;    // [2][512][64] h1^T parity (k-major)
constexpr int OFF_H1T  = OFF_H1 + 2 * HB;    // [2][64][512] h1 b-major parity
constexpr int OFF_BSUM = OFF_H1T + 2 * HB;   // [2][2048] b_ih+b_hh
constexpr int OFF_BAR  = OFF_BSUM + 2 * 4 * H;  // 32 uints barrier state
}  // namespace

// coherent (bypass L1/L2, IF$-served) primitives for barrier & act stores
__device__ __forceinline__ unsigned coh_load_u32(const unsigned* p) {
  unsigned v;
  asm volatile(
      "global_load_dword %0, %1, off sc0 sc1\n\t"
      "s_waitcnt vmcnt(0)"
      : "=v"(v)
      : "v"(p)
      : "memory");
  return v;
}
__device__ __forceinline__ void coh_store1(float* p, float v) {
  asm volatile("global_store_dword %0, %1, off sc0 sc1" ::"v"(p), "v"(v)
               : "memory");
}

__global__ __launch_bounds__(NTHR) void init_ws_kernel(
    float* __restrict__ ws, const float* __restrict__ b_ih,
    const float* __restrict__ b_hh) {
  int idx = blockIdx.x * blockDim.x + threadIdx.x;
  for (int f = idx; f < OFF_BSUM; f += NBLK * NTHR) ws[f] = 0.f;
  if (idx < 2 * 4 * H) ws[OFF_BSUM + idx] = b_ih[idx] + b_hh[idx];
  if (idx < 32) reinterpret_cast<unsigned*>(ws + OFF_BAR)[idx] = 0u;
}

__device__ __forceinline__ float sigm(float x) {
  return 1.f / (1.f + __expf(-x));
}
__device__ __forceinline__ float tanh_fast(float x) {
  float e = __expf(-2.f * fabsf(x));
  float t = (1.f - e) / (1.f + e);
  return x < 0.f ? -t : t;
}

__global__ __launch_bounds__(NTHR, 2) void lstm_kernel(
    const float* __restrict__ x, const float* __restrict__ w_in,
    const float* __restrict__ b_in, const float* __restrict__ w_ih,
    const float* __restrict__ w_hh, const float* __restrict__ w_out,
    const float* __restrict__ b_out, float* __restrict__ ws,
    float* __restrict__ out) {
  __shared__ float s_w[2 * 8 * 64 * P];  // 80 KB persistent gate weights
  __shared__ float s_red[4096];          // 16 KB reduction scratch
  __shared__ float s_g[512];             // 2 KB gate pre-activations

  const int tid = threadIdx.x;
  const int wg = blockIdx.x;
  unsigned* const bar = reinterpret_cast<unsigned*>(ws + OFF_BAR);

  // ---- persistent weight load into LDS (read once; fence-immune) ----
#pragma unroll
  for (int i = 0; i < 8; ++i) {
    int idx = i * 512 + tid;  // float4 unit 0..4095
    int l = idx >> 11;
    int rem = idx & 2047;
    int r = rem >> 8;
    int k0 = (rem & 255) * 4;
    int grow = (r >> 1) * 512 + wg * 2 + (r & 1);
    const float* srcp =
        (k0 < 512) ? (w_ih + ((size_t)l * 4 * H + grow) * H + k0)
                   : (w_hh + ((size_t)l * 4 * H + grow) * H + (k0 - 512));
    float4 v = *reinterpret_cast<const float4*>(srcp);
    float arr[4] = {v.x, v.y, v.z, v.w};
#pragma unroll
    for (int j = 0; j < 4; ++j) {
      int k = k0 + j;
      int c = k >> 6, ss = k & 63;
      s_w[((l * 8 + r) * 64 + ss) * P + c] = arr[j];
    }
  }

  // ---- register-cache fixed-address weights (invalidation-immune) ----
  float4 wo_reg[8];  // w_out row for out_block
  {
    const int o = tid & 31, ks = tid >> 5;
    const float* wrow = w_out + (size_t)((wg & 3) * 32 + o) * H + ks * 32;
#pragma unroll
    for (int j = 0; j < 8; ++j)
      wo_reg[j] = *reinterpret_cast<const float4*>(wrow + j * 4);
  }
  const float bo_reg = b_out[(wg & 3) * 32 + (tid & 31)];
  float4 wi_reg[8];  // w_in row for inp_block
  {
    const int cc = (tid >> 6) & 1, ks = tid >> 7;
    const float* wrow = w_in + (size_t)(wg * 2 + cc) * I_DIM + ks * 32;
#pragma unroll
    for (int j = 0; j < 8; ++j)
      wi_reg[j] = *reinterpret_cast<const float4*>(wrow + j * 4);
  }
  const float bi_reg = b_in[wg * 2 + ((tid >> 6) & 1)];
  __syncthreads();

  // ---- grid barrier: sc-coherent polls; acquire fence (L1+L2 inv) at exit
  auto gridbar = [&]() {
    __syncthreads();
    if (tid == 0) {
      if (coh_load_u32(bar + 18) == 0u) {
        unsigned gen = coh_load_u32(bar + 17);
        unsigned grp = (unsigned)wg & 15u;
        unsigned prev = __hip_atomic_fetch_add(bar + grp, 1u, __ATOMIC_RELAXED,
                                               __HIP_MEMORY_SCOPE_AGENT);
        bool done = false;
        if (prev == 15u) {
          __hip_atomic_store(bar + grp, 0u, __ATOMIC_RELAXED,
                             __HIP_MEMORY_SCOPE_AGENT);
          unsigned mprev = __hip_atomic_fetch_add(
              bar + 16, 1u, __ATOMIC_RELAXED, __HIP_MEMORY_SCOPE_AGENT);
          if (mprev == 15u) {
            __hip_atomic_store(bar + 16, 0u, __ATOMIC_RELAXED,
                               __HIP_MEMORY_SCOPE_AGENT);
            __hip_atomic_fetch_add(bar + 17, 1u, __ATOMIC_RELEASE,
                                   __HIP_MEMORY_SCOPE_AGENT);
            done = true;
          }
        }
        if (!done) {
          int spin = 0;
          while (coh_load_u32(bar + 17) == gen) {
            __builtin_amdgcn_s_sleep(1);
            if (++spin > (1 << 16)) {  // failsafe: fast-fail, don't hang
              __hip_atomic_store(bar + 18, 1u, __ATOMIC_RELAXED,
                                 __HIP_MEMORY_SCOPE_AGENT);
              break;
            }
          }
        }
      }
    }
    __syncthreads();
    // one per-step acquire: invalidate L1+L2 so cached act reads see the
    // sc-written values published before the barrier.
    __builtin_amdgcn_fence(__ATOMIC_ACQUIRE, "agent");
  };

  // ---- out(tt) from h1T (b-major); cached loads + register weights ----
  auto out_block = [&](int tt, int parb) {
    const int ks = tid >> 5;
    const int b = wg >> 2;
    const float* hrow = ws + OFF_H1T + parb * HB + b * 512 + ks * 32;
    float part = 0.f;
#pragma unroll
    for (int k4 = 0; k4 < 8; ++k4) {
      float4 hv = *reinterpret_cast<const float4*>(hrow + k4 * 4);
      part += wo_reg[k4].x * hv.x + wo_reg[k4].y * hv.y + wo_reg[k4].z * hv.z +
              wo_reg[k4].w * hv.w;
    }
    s_red[tid] = part;
    __syncthreads();
    if (tid < 32) {
      float sum = 0.f;
#pragma unroll
      for (int kk = 0; kk < 16; ++kk) sum += s_red[kk * 32 + tid];
      int ii = (wg & 3) * 32 + tid;
      out[((size_t)tt * B + b) * I_DIM + ii] = sum + bo_reg;
    }
    __syncthreads();
  };

  // ---- inp(tn) = sigmoid(x[tn] @ w_in^T + b_in) -> cols {2wg,2wg+1} ----
  auto inp_block = [&](int tn, int par) {
    const int b = tid & 63, ks = tid >> 7;
    const float* xsrc = x + ((size_t)tn * B + b) * I_DIM + ks * 32;
    float part = 0.f;
#pragma unroll
    for (int k4 = 0; k4 < 8; ++k4) {
      float4 xv = *reinterpret_cast<const float4*>(xsrc + k4 * 4);
      part += xv.x * wi_reg[k4].x + xv.y * wi_reg[k4].y + xv.z * wi_reg[k4].z +
              xv.w * wi_reg[k4].w;
    }
    s_red[tid] = part;
    __syncthreads();
    if (tid < 128) {
      float v = s_red[tid] + s_red[tid + 128] + s_red[tid + 256] +
                s_red[tid + 384];
      int col2 = wg * 2 + (tid >> 6), b2 = tid & 63;
      coh_store1(ws + OFF_INP + par * HB + col2 * 64 + b2, sigm(v + bi_reg));
    }
    __syncthreads();
  };

  // ---- gates gemv: 8 rows x 64 b, K=1024 = [lo(512);hi(512)], k-major.
  // Weights from persistent LDS; acts via CACHED loads, group-prefetched.
  auto gemv = [&](const float* __restrict__ lo, const float* __restrict__ hi,
                  const int layer) {
    const int s = tid >> 3;  // k-slice 0..63
    const int tb = tid & 7;  // batch octet
    const int wbase = ((layer * 8) * 64 + s) * P;
    float acc[64];
#pragma unroll
    for (int q = 0; q < 64; ++q) acc[q] = 0.f;

    float4 a_cur[4][2], a_nxt[4][2];
#pragma unroll
    for (int c = 0; c < 4; ++c) {
      const float* p = lo + c * 4096 + s * 64 + tb * 8;
      a_cur[c][0] = *reinterpret_cast<const float4*>(p);
      a_cur[c][1] = *reinterpret_cast<const float4*>(p + 4);
    }
#pragma unroll
    for (int g = 0; g < 4; ++g) {
      if (g < 3) {
#pragma unroll
        for (int cc = 0; cc < 4; ++cc) {
          const int c = (g + 1) * 4 + cc;
          const float* p =
              (c < 8 ? lo + c * 4096 : hi + (c - 8) * 4096) + s * 64 + tb * 8;
          a_nxt[cc][0] = *reinterpret_cast<const float4*>(p);
          a_nxt[cc][1] = *reinterpret_cast<const float4*>(p + 4);
        }
      }
      float4 wr[8];
#pragma unroll
      for (int r = 0; r < 8; ++r)
        wr[r] = *reinterpret_cast<const float4*>(
            &s_w[wbase + r * (64 * P) + g * 4]);
#pragma unroll
      for (int cc = 0; cc < 4; ++cc) {
        float av[8] = {a_cur[cc][0].x, a_cur[cc][0].y, a_cur[cc][0].z,
                       a_cur[cc][0].w, a_cur[cc][1].x, a_cur[cc][1].y,
                       a_cur[cc][1].z, a_cur[cc][1].w};
#pragma unroll
        for (int r = 0; r < 8; ++r) {
          float w = (cc == 0) ? wr[r].x
                  : (cc == 1) ? wr[r].y
                  : (cc == 2) ? wr[r].z
                              : wr[r].w;
#pragma unroll
          for (int bb = 0; bb < 8; ++bb)
            acc[r * 8 + bb] = fmaf(w, av[bb], acc[r * 8 + bb]);
        }
      }
#pragma unroll
      for (int cc = 0; cc < 4; ++cc) {
        a_cur[cc][0] = a_nxt[cc][0];
        a_cur[cc][1] = a_nxt[cc][1];
      }
    }

    // ---- exchange-and-halve reduction over lane bits 3..5 ----
    const int lane = tid & 63;
    const bool b3 = (lane & 8) != 0;
    const bool b4 = (lane & 16) != 0;
    const bool b5 = (lane & 32) != 0;
    float v32[32];
#pragma unroll
    for (int go = 0; go < 4; ++go)
#pragma unroll
      for (int j = 0; j < 8; ++j) {
        float lc = acc[(2 * go + 0) * 8 + j];
        float hc = acc[(2 * go + 1) * 8 + j];
        float lo_o = __shfl_xor(lc, 8, 64);
        float hi_o = __shfl_xor(hc, 8, 64);
        v32[go * 8 + j] = b3 ? (hc + hi_o) : (lc + lo_o);
      }
    float v16[16];
#pragma unroll
    for (int go = 0; go < 2; ++go)
#pragma unroll
      for (int j = 0; j < 8; ++j) {
        float lc = v32[(2 * go + 0) * 8 + j];
        float hc = v32[(2 * go + 1) * 8 + j];
        float lo_o = __shfl_xor(lc, 16, 64);
        float hi_o = __shfl_xor(hc, 16, 64);
        v16[go * 8 + j] = b4 ? (hc + hi_o) : (lc + lo_o);
      }
    float fin[8];
#pragma unroll
    for (int j = 0; j < 8; ++j) {
      float lc = v16[j];
      float hc = v16[8 + j];
      float lo_o = __shfl_xor(lc, 32, 64);
      float hi_o = __shfl_xor(hc, 32, 64);
      fin[j] = b5 ? (hc + hi_o) : (lc + lo_o);
    }
    const int wv = tid >> 6;
    const int sigma = (lane >> 3) & 7;
    float* dst = s_red + wv * 512 + sigma * 64 + tb * 8;
    *reinterpret_cast<float4*>(dst) = make_float4(fin[0], fin[1], fin[2], fin[3]);
    *reinterpret_cast<float4*>(dst + 4) =
        make_float4(fin[4], fin[5], fin[6], fin[7]);
    __syncthreads();
    {
      const float* bsum_l = ws + OFF_BSUM + layer * 4 * H;
      float sum = 0.f;
#pragma unroll
      for (int w8 = 0; w8 < 8; ++w8) sum += s_red[w8 * 512 + tid];
      int r = tid >> 6;
      int grow = (r >> 1) * 512 + wg * 2 + (r & 1);
      s_g[tid] = sum + bsum_l[grow];  // s_g[r*64+b]
    }
    __syncthreads();
  };

  float cs0 = 0.f, cs1 = 0.f;  // tid<128 owns (col=2wg+(tid>>6), b=tid&63)

  auto cell0_update = [&](float* dst) {
    if (tid < 128) {
      const int cc = tid >> 6, b = tid & 63, col = wg * 2 + cc;
      float ig = sigm(s_g[(0 + cc) * 64 + b]);
      float fg = sigm(s_g[(2 + cc) * 64 + b]);
      float gt = tanh_fast(s_g[(4 + cc) * 64 + b]);
      float og = sigm(s_g[(6 + cc) * 64 + b]);
      cs0 = fg * cs0 + ig * gt;
      coh_store1(dst + col * 64 + b, og * tanh_fast(cs0));
    }
  };
  auto cell1_update = [&](int p) {
    if (tid < 128) {
      const int cc = tid >> 6, b = tid & 63, col = wg * 2 + cc;
      float ig = sigm(s_g[(0 + cc) * 64 + b]);
      float fg = sigm(s_g[(2 + cc) * 64 + b]);
      float gt = tanh_fast(s_g[(4 + cc) * 64 + b]);
      float og = sigm(s_g[(6 + cc) * 64 + b]);
      cs1 = fg * cs1 + ig * gt;
      float h = og * tanh_fast(cs1);
      coh_store1(ws + OFF_H1 + p * HB + col * 64 + b, h);    // k-major
      coh_store1(ws + OFF_H1T + p * HB + b * 512 + col, h);  // b-major
    }
  };

  // ---------------- prologue ----------------
  inp_block(0, 0);
  inp_block(1, 1);
  gridbar();
  gemv(ws + OFF_INP + 0 * HB, ws + OFF_H0 + 1 * HB, 0);  // h0(-1)=par1 zeros
  cell0_update(ws + OFF_H0 + 0 * HB);
  gridbar();

  // ---------------- main loop: one barrier per step ----------------
  for (int t = 0; t < T_STEPS; ++t) {
    const int p = t & 1;
    gemv(ws + OFF_H0 + p * HB, ws + OFF_H1 + (1 - p) * HB, 1);
    cell1_update(p);
    if (t > 0) out_block(t - 1, 1 - p);
    if (t + 1 < T_STEPS) {
      gemv(ws + OFF_INP + (1 - p) * HB, ws + OFF_H0 + p * HB, 0);
      cell0_update(ws + OFF_H0 + (1 - p) * HB);
    }
    if (t + 2 < T_STEPS) inp_block(t + 2, p);
    gridbar();
  }
  out_block(T_STEPS - 1, 1);
}

extern "C" void kernel_launch(void* const* d_in, const int* in_sizes, int n_in,
                              void* d_out, int out_size, void* d_ws,
                              size_t ws_size, hipStream_t stream) {
  const float* x     = (const float*)d_in[0];
  const float* w_in  = (const float*)d_in[1];
  const float* b_in  = (const float*)d_in[2];
  const float* w_ih  = (const float*)d_in[3];
  const float* w_hh  = (const float*)d_in[4];
  const float* b_ih  = (const float*)d_in[5];
  const float* b_hh  = (const float*)d_in[6];
  const float* w_out = (const float*)d_in[7];
  const float* b_out = (const float*)d_in[8];
  float* ws   = (float*)d_ws;
  float* outp = (float*)d_out;

  hipLaunchKernelGGL(init_ws_kernel, dim3(NBLK), dim3(NTHR), 0, stream, ws,
                     b_ih, b_hh);
  hipLaunchKernelGGL(lstm_kernel, dim3(NBLK), dim3(NTHR), 0, stream, x, w_in,
                     b_in, w_ih, w_hh, w_out, b_out, ws, outp);
}